// Round 11
// baseline (195.697 us; speedup 1.0000x reference)
//
#include <hip/hip_runtime.h>

#define SEQ_N 1024
#define BATCH 64
#define NW    4            // waves per block (per batch element)
#define RPL   4            // rows per lane: 4 waves * 64 lanes * 4 = 1024 rows
#define KSL   32           // epoch length (steps between barriers)
#define DELTA 96           // column delay between consecutive waves
#define LAG   33           // DELTA - 63: consumer step s reads producer step s-LAG
#define RINGM 128          // ring slots (power of 2; recycles every 4 epochs)
#define PAD_F 352          // front pad: max off = 3*96+63 = 351
#define PAD_B 352          // back pad: max y index = 1375 -> 352-off+1375 <= 1727

// Wave-wide shift-up-by-1 in one instruction (DPP wave_shr:1, ctrl 0x138).
// bound_ctrl=false -> lane 0 takes `fill` (INF) = top-row boundary for free.
__device__ __forceinline__ float wave_shr1(float v, float fill) {
    return __int_as_float(__builtin_amdgcn_update_dpp(
        __float_as_int(fill), __float_as_int(v), 0x138, 0xF, 0xF, false));
}

// 4 waves per DTW matrix, barrier per 32-step epoch (43 barriers total).
// Wave w owns rows [w*256,+256), lane l owns rows w*256+4l..+4. Lane (w,l)
// at step s computes column j = s - (96w + l).
//
// Ring (per wave pair, 128 slots, slot = step & 127), all I/O per-step:
//  - consumer (w,0) at step s reads slot (s-33)&127. Producer p=s-33 is in
//    producer-epoch floor(p/32) <= E-1 (p <= 32E-2), so data crossed >= 1
//    barrier. For the first active consumer step s=96w: p=96w-33 was written
//    in epoch 3w-2, consumed in epoch 3w -> 2 barriers. Never reads garbage
//    that gets consumed (consumer active at s <=> producer active at s-33).
//  - WAR: producer epoch E writes p in [32E,32E+31], overwriting p-128
//    (epoch E-4), last read at consumer step p-128+33 = p-95 (epochs
//    E-3/E-2) -> >= 2 barriers before the overwrite. Safe.
//
// Corner seed: D[0,0] needs up=0 at (epoch 0, k2=0, tid 0); diag_top is then
// restored to INF so cell (0,1) doesn't inherit 0 through the diag path.
__global__ __launch_bounds__(256, 1) void dtw_kernel(const float* __restrict__ x,
                                                     const float* __restrict__ y,
                                                     float* __restrict__ dists) {
    __shared__ float sy_raw[PAD_F + SEQ_N + PAD_B];
    __shared__ float ring[NW - 1][RINGM];

    const int b   = blockIdx.x;
    const int tid = threadIdx.x;
    const int w   = tid >> 6;        // wave id 0..3
    const int l   = tid & 63;        // lane id
    const float INF = 3.0e37f;
    const int  off = w * DELTA + l;  // column delay of this lane
    const bool is_tid0 = (tid == 0);

    // zero pads
    for (int i = tid; i < PAD_F; i += 256) sy_raw[i] = 0.0f;
    for (int i = tid; i < PAD_B; i += 256) sy_raw[PAD_F + SEQ_N + i] = 0.0f;
    // stage y (one float4 per thread)
    ((float4*)(sy_raw + PAD_F))[tid] = ((const float4*)(y + b * SEQ_N))[tid];
    // this lane's 4 x-rows (one float4)
    const float4 xv = *((const float4*)(x + b * SEQ_N + w * 256 + l * RPL));
    const float xr0 = xv.x, xr1 = xv.y, xr2 = xv.z, xr3 = xv.w;
    __syncthreads();

    const float* const yp = sy_raw + PAD_F - off;   // yp[s] == y[s - off]

    float c0 = INF, c1 = INF, c2 = INF, c3 = INF;   // col[0..3]
    float diag_top = INF, bottom = INF;

// One 32-step epoch; per-step LDS I/O (no batched arrays) so the compiler
// can pipeline ds_reads through the epoch instead of serializing them at
// the barrier. Ring addresses are wave-uniform (SALU + v_mov).
#define EPOCH(MASKED, FIRST, S0)                                             \
  {                                                                          \
    __syncthreads();                                                         \
    _Pragma("unroll")                                                        \
    for (int k2 = 0; k2 < KSL; ++k2) {                                       \
      const float up_dpp = wave_shr1(bottom, INF);                           \
      float upv;                                                             \
      if (w > 0) {                                                           \
        const float rv = ring[w - 1][((S0) + k2 - LAG) & (RINGM - 1)];       \
        upv = (l == 0) ? rv : up_dpp;                                        \
      } else {                                                               \
        upv = up_dpp;                                                        \
      }                                                                      \
      if ((FIRST) && k2 == 0 && is_tid0) upv = 0.0f;  /* seed D[0,0]=d */    \
      const float yj = yp[(S0) + k2];                                        \
      bool act = true;                                                       \
      if (MASKED) act = ((unsigned)((S0) + k2 - off) < (unsigned)SEQ_N);     \
      if (act) {                                                             \
        const float d0 = xr0 - yj, d1 = xr1 - yj,                            \
                    d2 = xr2 - yj, d3 = xr3 - yj;                            \
        const float t0 = diag_top + fabsf(d0);                               \
        const float t1 = c0 + fabsf(d1);                                     \
        const float t2 = c1 + fabsf(d2);                                     \
        const float t3 = c2 + fabsf(d3);                                     \
        float v = upv;                                                       \
        v = fminf(fminf(t0, c0), v) + fabsf(d0); c0 = v;                     \
        v = fminf(fminf(t1, c1), v) + fabsf(d1); c1 = v;                     \
        v = fminf(fminf(t2, c2), v) + fabsf(d2); c2 = v;                     \
        v = fminf(fminf(t3, c3), v) + fabsf(d3); c3 = v;                     \
        diag_top = upv; bottom = v;                                          \
      }                                                                      \
      if ((FIRST) && k2 == 0 && is_tid0) diag_top = INF; /* un-contaminate */\
      if (w < NW - 1 && l == 63)                                             \
        ring[w][((S0) + k2) & (RINGM - 1)] = bottom;                         \
    }                                                                        \
  }

    int s0 = 0;
    // epoch 0: carries the corner seed
    EPOCH(true, true, 0); s0 = 32;
    // epochs 1..10: ramp-up (max off = 351; all-active from step 351)
    for (int e = 1; e <= 10; ++e) { EPOCH(true, false, s0); s0 += 32; }
    // epochs 11..31: steady (S0 in [352, 992]; steps <= 1023, all active)
    for (int e = 11; e <= 31; ++e) { EPOCH(false, false, s0); s0 += 32; }
    // epochs 32..42: ramp-down (last active step = 1023 + 351 = 1374)
    for (int e = 32; e <= 42; ++e) { EPOCH(true, false, s0); s0 += 32; }
#undef EPOCH

    // D[1023,1023] lives in wave 3 lane 63's c3
    if (tid == 255) dists[b] = c3 * (1.0f / (2.0f * (float)SEQ_N));
}

// Mean over the 64 per-batch distances -> single float output.
__global__ void dtw_reduce_kernel(const float* __restrict__ dists,
                                  float* __restrict__ out) {
    float v = dists[threadIdx.x] * (1.0f / (float)BATCH);
    #pragma unroll
    for (int o = 32; o > 0; o >>= 1) v += __shfl_down(v, o);
    if (threadIdx.x == 0) out[0] = v;
}

extern "C" void kernel_launch(void* const* d_in, const int* in_sizes, int n_in,
                              void* d_out, int out_size, void* d_ws, size_t ws_size,
                              hipStream_t stream) {
    const float* x = (const float*)d_in[0];
    const float* y = (const float*)d_in[1];
    float* out = (float*)d_out;
    float* dists = (float*)d_ws;  // 64 floats of scratch

    dtw_kernel<<<BATCH, 256, 0, stream>>>(x, y, dists);
    dtw_reduce_kernel<<<1, BATCH, 0, stream>>>(dists, out);
}

// Round 12
// 89.020 us; speedup vs baseline: 2.1983x; 2.1983x over previous
//
#include <hip/hip_runtime.h>

#define SEQ_N 1024
#define BATCH 64
#define NW    4            // waves per block (per batch element)
#define RPL   4            // rows per lane: 4 waves * 64 lanes * 4 = 1024 rows
#define KSL   32           // epoch length (steps between barriers)
#define DELTA 96           // column delay between consecutive waves
#define LAG   33           // DELTA-63: consumer step s reads producer step s-33
#define RINGN 160          // 128 slots + 32 mirror (wrap-free batched reads)
#define PAD_F 352          // front pad: max off = 3*96+63 = 351
#define PAD_B 384          // back pad: max y index 1407 -> 352+1407 < 1760

// Wave-wide shift-up-by-1 in one instruction (DPP wave_shr:1, ctrl 0x138).
// bound_ctrl=false -> lane 0 takes `fill` (INF) = top-row boundary for free.
__device__ __forceinline__ float wave_shr1(float v, float fill) {
    return __int_as_float(__builtin_amdgcn_update_dpp(
        __float_as_int(fill), __float_as_int(v), 0x138, 0xF, 0xF, false));
}

// 4 waves per DTW matrix; barrier per 32-step epoch (43 barriers, was 84 at
// KSL=16). Same verified structure as the 84.6us kernel: batched register
// arrays for ring-read / y-prefetch / bottoms (the R11 lesson: per-step LDS
// reads serialize ~120cy each; batched reads amortize to ~6cy).
//
// Wave w owns rows [w*256,+256), lane l rows w*256+4l..+4; lane (w,l) at
// step s computes column j = s - (96w + l).
//
// Ring (128 slots, slot = producer step & 127, batched):
//  RAW: producer epoch E_p writes slots at region end; consumer reads p at
//    head of epoch floor((p+33)/32) >= E_p+1 -> >= 1 barrier between.
//  WAR: slot p reused at p+128 (epoch E_p+4); last read head of E_p+2 ->
//    barriers E_p+2..E_p+4 between read and overwrite.
//  Wrap: rbase = (32E-33)&127 in {95,127,31,63}; only 127 wraps, reading
//    [127..158]; mirror [128..159] = copy of slots 0..31, written exactly by
//    the mm==0 epochs (E_p = 0 mod 4) that produce those slots.
//
// Corner seed: D[0,0] needs up=0 at (epoch 0, k2=0, tid 0); diag_top is then
// restored to INF so cell (0,1) doesn't inherit 0 through the diag path.
__global__ __launch_bounds__(256, 1) void dtw_kernel(const float* __restrict__ x,
                                                     const float* __restrict__ y,
                                                     float* __restrict__ dists) {
    __shared__ float sy_raw[PAD_F + SEQ_N + PAD_B];
    __shared__ float ring[NW - 1][RINGN];

    const int b   = blockIdx.x;
    const int tid = threadIdx.x;
    const int w   = tid >> 6;        // wave id 0..3
    const int l   = tid & 63;        // lane id
    const float INF = 3.0e37f;
    const int  off = w * DELTA + l;  // column delay of this lane
    const bool is_ring_l0 = (l == 0) && (w > 0);
    const bool is_tid0 = (tid == 0);

    // zero pads
    for (int i = tid; i < PAD_F; i += 256) sy_raw[i] = 0.0f;
    for (int i = tid; i < PAD_B; i += 256) sy_raw[PAD_F + SEQ_N + i] = 0.0f;
    // stage y (one float4 per thread)
    ((float4*)(sy_raw + PAD_F))[tid] = ((const float4*)(y + b * SEQ_N))[tid];
    // this lane's 4 x-rows (one float4)
    const float4 xv = *((const float4*)(x + b * SEQ_N + w * 256 + l * RPL));
    const float xr0 = xv.x, xr1 = xv.y, xr2 = xv.z, xr3 = xv.w;
    __syncthreads();

    const float* const yp = sy_raw + PAD_F - off;   // yp[s] == y[s - off]

    float c0 = INF, c1 = INF, c2 = INF, c3 = INF;   // col[0..3]
    float diag_top = INF, bottom = INF;
    float yA[KSL], yB[KSL], rb[KSL], bt[KSL];

    // prologue: y values for epoch 0
    #pragma unroll
    for (int k = 0; k < KSL; ++k) yA[k] = yp[k];

// One 32-step epoch. YU = y regs for this epoch, YF = filled with next
// epoch's y. Ring reads batched right after the barrier; bottoms collected
// in bt[] and written (plus mirror on mm==0 epochs) at epoch end.
#define EPOCH(MASKED, FIRST, S0, YU, YF)                                     \
  {                                                                          \
    __syncthreads();                                                         \
    if (w > 0) {                                                             \
      int rbase = ((S0) & 127) + 95; if (rbase >= 128) rbase -= 128;         \
      const float* rp = ring[w - 1] + rbase;                                 \
      _Pragma("unroll")                                                      \
      for (int k2 = 0; k2 < KSL; ++k2) rb[k2] = rp[k2];                      \
    } else {                                                                 \
      _Pragma("unroll")                                                      \
      for (int k2 = 0; k2 < KSL; ++k2) rb[k2] = INF;                         \
    }                                                                        \
    _Pragma("unroll")                                                        \
    for (int k2 = 0; k2 < KSL; ++k2) YF[k2] = yp[(S0) + KSL + k2];           \
    _Pragma("unroll")                                                        \
    for (int k2 = 0; k2 < KSL; ++k2) {                                       \
      const float up_dpp = wave_shr1(bottom, INF);                           \
      float upv = is_ring_l0 ? rb[k2] : up_dpp;                              \
      if ((FIRST) && k2 == 0 && is_tid0) upv = 0.0f;  /* seed D[0,0]=d */    \
      const float yj = YU[k2];                                               \
      bool act = true;                                                       \
      if (MASKED) act = ((unsigned)((S0) + k2 - off) < (unsigned)SEQ_N);     \
      if (act) {                                                             \
        const float d0 = xr0 - yj, d1 = xr1 - yj,                            \
                    d2 = xr2 - yj, d3 = xr3 - yj;                            \
        const float t0 = diag_top + fabsf(d0);                               \
        const float t1 = c0 + fabsf(d1);                                     \
        const float t2 = c1 + fabsf(d2);                                     \
        const float t3 = c2 + fabsf(d3);                                     \
        float v = upv;                                                       \
        v = fminf(fminf(t0, c0), v) + fabsf(d0); c0 = v;                     \
        v = fminf(fminf(t1, c1), v) + fabsf(d1); c1 = v;                     \
        v = fminf(fminf(t2, c2), v) + fabsf(d2); c2 = v;                     \
        v = fminf(fminf(t3, c3), v) + fabsf(d3); c3 = v;                     \
        diag_top = upv; bottom = v;                                          \
      }                                                                      \
      if ((FIRST) && k2 == 0 && is_tid0) diag_top = INF; /* un-contaminate */\
      bt[k2] = bottom;                                                       \
    }                                                                        \
    if (w < NW - 1 && l == 63) {                                             \
      const int mm = (S0) & 127;                                             \
      float* wp = ring[w] + mm;                                              \
      _Pragma("unroll")                                                      \
      for (int k2 = 0; k2 < KSL; ++k2) wp[k2] = bt[k2];                      \
      if (mm == 0) {                                                         \
        _Pragma("unroll")                                                    \
        for (int k2 = 0; k2 < KSL; ++k2) ring[w][128 + k2] = bt[k2];         \
      }                                                                      \
    }                                                                        \
  }

    // epoch 0: carries the corner seed
    EPOCH(true, true, 0, yA, yB);
    int s0 = 32;
    // epochs 1..10: ramp-up (max off = 351; all-active from step 351)
    for (int it = 0; it < 5; ++it) {
        EPOCH(true, false, s0, yB, yA);
        EPOCH(true, false, s0 + 32, yA, yB);
        s0 += 64;
    }
    // epochs 11..30: steady (S0 in [352, 960]; S0+31 <= 991 <= 1023)
    for (int it = 0; it < 10; ++it) {
        EPOCH(false, false, s0, yB, yA);
        EPOCH(false, false, s0 + 32, yA, yB);
        s0 += 64;
    }
    // epochs 31..42: ramp-down (last active step = 1023 + 351 = 1374)
    for (int it = 0; it < 6; ++it) {
        EPOCH(true, false, s0, yB, yA);
        EPOCH(true, false, s0 + 32, yA, yB);
        s0 += 64;
    }
#undef EPOCH

    // D[1023,1023] lives in wave 3 lane 63's c3
    if (tid == 255) dists[b] = c3 * (1.0f / (2.0f * (float)SEQ_N));
}

// Mean over the 64 per-batch distances -> single float output.
__global__ void dtw_reduce_kernel(const float* __restrict__ dists,
                                  float* __restrict__ out) {
    float v = dists[threadIdx.x] * (1.0f / (float)BATCH);
    #pragma unroll
    for (int o = 32; o > 0; o >>= 1) v += __shfl_down(v, o);
    if (threadIdx.x == 0) out[0] = v;
}

extern "C" void kernel_launch(void* const* d_in, const int* in_sizes, int n_in,
                              void* d_out, int out_size, void* d_ws, size_t ws_size,
                              hipStream_t stream) {
    const float* x = (const float*)d_in[0];
    const float* y = (const float*)d_in[1];
    float* out = (float*)d_out;
    float* dists = (float*)d_ws;  // 64 floats of scratch

    dtw_kernel<<<BATCH, 256, 0, stream>>>(x, y, dists);
    dtw_reduce_kernel<<<1, BATCH, 0, stream>>>(dists, out);
}